// Round 3
// baseline (790.562 us; speedup 1.0000x reference)
//
#include <hip/hip_runtime.h>

// ---------------------------------------------------------------------------
// DecoderLayer (B=2,S=2048,D=1024,H=16,HD=64,FFN=4096).
// R3: I/O dtype = fp32 (per reference); compute = bf16 MFMA + fp32 accum.
//   - weight transposes convert f32 -> bf16 into ws
//   - GEMM A-operand staging converts f32->bf16 when A is an original input
//   - all intermediates bf16; final add_ln writes fp32 to d_out
// ---------------------------------------------------------------------------

typedef unsigned short u16;
typedef short v8s __attribute__((ext_vector_type(8)));
typedef float v4f __attribute__((ext_vector_type(4)));

#define LDK 72
#define LOG2E 1.44269504088896340736f

__device__ __forceinline__ float b2f(u16 h) {
    return __uint_as_float(((unsigned)h) << 16);
}
__device__ __forceinline__ u16 f2b(float f) {
    unsigned u = __float_as_uint(f);
    u += 0x7fffu + ((u >> 16) & 1u);   // RNE
    return (u16)(u >> 16);
}
__device__ __forceinline__ v8s pack8(const float* p) {
    float4 f0 = *(const float4*)p;
    float4 f1 = *(const float4*)(p + 4);
    v8s r;
    r[0] = (short)f2b(f0.x); r[1] = (short)f2b(f0.y);
    r[2] = (short)f2b(f0.z); r[3] = (short)f2b(f0.w);
    r[4] = (short)f2b(f1.x); r[5] = (short)f2b(f1.y);
    r[6] = (short)f2b(f1.z); r[7] = (short)f2b(f1.w);
    return r;
}

// ---------------------------------------------------------------------------
// fp32 src[R][C] -> bf16 dst[C][R].  grid (C/32, R/32), 256 thr.
// ---------------------------------------------------------------------------
__global__ __launch_bounds__(256) void transpose_f2b(
    const float* __restrict__ src, u16* __restrict__ dst, int R, int C)
{
    __shared__ u16 tile[32][33];
    const int t  = threadIdx.x;
    const int tx = t & 31, ty = t >> 5;           // ty in 0..7
    const int r0 = blockIdx.y * 32, c0 = blockIdx.x * 32;
#pragma unroll
    for (int i = 0; i < 32; i += 8)
        tile[ty + i][tx] = f2b(src[(size_t)(r0 + ty + i) * C + c0 + tx]);
    __syncthreads();
#pragma unroll
    for (int i = 0; i < 32; i += 8)
        dst[(size_t)(c0 + ty + i) * R + r0 + tx] = tile[tx][ty + i];
}

// ---------------------------------------------------------------------------
// bias concat (fp32): sab[3072] = bq|bk|bv ; cakvb[2048] = ca_bk|ca_bv
// ---------------------------------------------------------------------------
__global__ __launch_bounds__(256) void prep_bias(
    const float* __restrict__ bq, const float* __restrict__ bk, const float* __restrict__ bv,
    const float* __restrict__ cbk, const float* __restrict__ cbv,
    float* __restrict__ sab, float* __restrict__ cakvb)
{
    int i = blockIdx.x * 256 + threadIdx.x;
    if (i < 1024) {
        sab[i]          = bq[i];
        sab[1024 + i]   = bk[i];
        sab[2048 + i]   = bv[i];
        cakvb[i]        = cbk[i];
        cakvb[1024 + i] = cbv[i];
    }
}

// ---------------------------------------------------------------------------
// GEMM: C[M,N] = A[M,K] * Bt[N,K]^T + bias[N]  (optional relu), C is bf16.
// AF32: A is fp32 (converted during staging), else A is bf16.
// grid (N/128, M/128), 256 threads (4 waves, 2x2 of 64x64 each).
// ---------------------------------------------------------------------------
template <int AF32>
__global__ __launch_bounds__(256) void gemm_bt(
    const void* __restrict__ Ap, const u16* __restrict__ Bt,
    const float* __restrict__ bias, u16* __restrict__ C,
    int M, int N, int K, int relu)
{
    __shared__ __align__(16) u16 Al[128 * LDK];
    __shared__ __align__(16) u16 Bl[128 * LDK];
    const int tid  = threadIdx.x;
    const int wave = tid >> 6, lane = tid & 63;
    const int quad = lane >> 4, tl = lane & 15;
    const int bm0 = blockIdx.y * 128, bn0 = blockIdx.x * 128;
    const int wm = (wave >> 1) * 64, wn = (wave & 1) * 64;

    const v4f z4 = {0.f, 0.f, 0.f, 0.f};
    v4f acc[4][4];
#pragma unroll
    for (int i = 0; i < 4; ++i)
#pragma unroll
        for (int j = 0; j < 4; ++j) acc[i][j] = z4;

    for (int kt = 0; kt < K; kt += 64) {
#pragma unroll
        for (int i = 0; i < 4; ++i) {
            int v = tid + i * 256;              // 0..1023
            int row = v >> 3, c = (v & 7) << 3; // 128 rows x 64 k
            if (AF32) {
                const float* Af = (const float*)Ap;
                *(v8s*)&Al[row * LDK + c] = pack8(&Af[(size_t)(bm0 + row) * K + kt + c]);
            } else {
                const u16* Ab = (const u16*)Ap;
                *(v8s*)&Al[row * LDK + c] = *(const v8s*)&Ab[(size_t)(bm0 + row) * K + kt + c];
            }
            *(v8s*)&Bl[row * LDK + c] = *(const v8s*)&Bt[(size_t)(bn0 + row) * K + kt + c];
        }
        __syncthreads();
#pragma unroll
        for (int kk = 0; kk < 2; ++kk) {
            const int ko = (kk << 5) + (quad << 3);
            v8s af[4], bf[4];
#pragma unroll
            for (int i = 0; i < 4; ++i) af[i] = *(const v8s*)&Al[(wm + i * 16 + tl) * LDK + ko];
#pragma unroll
            for (int i = 0; i < 4; ++i) bf[i] = *(const v8s*)&Bl[(wn + i * 16 + tl) * LDK + ko];
#pragma unroll
            for (int mi = 0; mi < 4; ++mi)
#pragma unroll
                for (int ni = 0; ni < 4; ++ni)
                    acc[mi][ni] = __builtin_amdgcn_mfma_f32_16x16x32_bf16(
                        af[mi], bf[ni], acc[mi][ni], 0, 0, 0);
        }
        __syncthreads();
    }
    // epilogue: C row = quad*4+r, col = tl   (m89/m91-verified C/D layout)
#pragma unroll
    for (int ni = 0; ni < 4; ++ni) {
        int col = bn0 + wn + ni * 16 + tl;
        float bv = bias[col];
#pragma unroll
        for (int mi = 0; mi < 4; ++mi) {
            int row0 = bm0 + wm + mi * 16 + (quad << 2);
#pragma unroll
            for (int r = 0; r < 4; ++r) {
                float vv = acc[mi][ni][r] + bv;
                if (relu) vv = fmaxf(vv, 0.f);
                C[(size_t)(row0 + r) * N + col] = f2b(vv);
            }
        }
    }
}

// ---------------------------------------------------------------------------
// Flash attention (all bf16 I/O). grid (S/64, B*H), 256 thr.
// ---------------------------------------------------------------------------
__global__ __launch_bounds__(256) void attn64(
    const u16* __restrict__ Q, int qs, const u16* __restrict__ Kp, int ks,
    const u16* __restrict__ Vp, int vs, u16* __restrict__ O, int os,
    int Sk, float scale)
{
    __shared__ __align__(16) u16 Kl[64 * LDK];   // [sk][hd]
    __shared__ __align__(16) u16 Vtl[64 * LDK];  // [hd][sk]  (transposed)
    __shared__ __align__(16) u16 Pl[64 * LDK];   // per-wave 16-row regions

    const int tid  = threadIdx.x;
    const int wave = tid >> 6, lane = tid & 63;
    const int quad = lane >> 4, tl = lane & 15;
    const int b = blockIdx.y >> 4, h = blockIdx.y & 15;

    const u16* qb = Q  + (size_t)(b * 2048) * qs + h * 64;
    const u16* kb = Kp + (size_t)(b * 2048) * ks + h * 64;
    const u16* vb = Vp + (size_t)(b * 2048) * vs + h * 64;
    u16*       ob = O  + (size_t)(b * 2048) * os + h * 64;
    const int qr0 = blockIdx.x * 64 + wave * 16;

    v8s qf[2];
#pragma unroll
    for (int kk = 0; kk < 2; ++kk)
        qf[kk] = *(const v8s*)&qb[(size_t)(qr0 + tl) * qs + kk * 32 + quad * 8];

    const v4f z4 = {0.f, 0.f, 0.f, 0.f};
    float m_r[4] = {-1e30f, -1e30f, -1e30f, -1e30f};
    float l_r[4] = {0.f, 0.f, 0.f, 0.f};
    v4f oacc[4] = {z4, z4, z4, z4};

    const int vhd = tid & 63, vsg = tid >> 6;

    for (int kt = 0; kt < Sk; kt += 64) {
#pragma unroll
        for (int i = 0; i < 2; ++i) {
            int v = tid + i * 256;
            int row = v >> 3, c = (v & 7) << 3;
            *(v8s*)&Kl[row * LDK + c] = *(const v8s*)&kb[(size_t)(kt + row) * ks + c];
        }
#pragma unroll
        for (int half = 0; half < 2; ++half) {
            v8s tmp;
#pragma unroll
            for (int j = 0; j < 8; ++j) {
                int sk = vsg * 16 + half * 8 + j;
                tmp[j] = (short)vb[(size_t)(kt + sk) * vs + vhd];
            }
            *(v8s*)&Vtl[vhd * LDK + vsg * 16 + half * 8] = tmp;
        }
        __syncthreads();

        v4f s[4];
#pragma unroll
        for (int nt = 0; nt < 4; ++nt) {
            v8s k0 = *(const v8s*)&Kl[(nt * 16 + tl) * LDK + quad * 8];
            v8s k1 = *(const v8s*)&Kl[(nt * 16 + tl) * LDK + 32 + quad * 8];
            v4f a = z4;
            a = __builtin_amdgcn_mfma_f32_16x16x32_bf16(qf[0], k0, a, 0, 0, 0);
            a = __builtin_amdgcn_mfma_f32_16x16x32_bf16(qf[1], k1, a, 0, 0, 0);
            s[nt] = a * scale;
        }

        float alpha[4];
#pragma unroll
        for (int r = 0; r < 4; ++r) {
            float mv = fmaxf(fmaxf(s[0][r], s[1][r]), fmaxf(s[2][r], s[3][r]));
            mv = fmaxf(mv, __shfl_xor(mv, 1));
            mv = fmaxf(mv, __shfl_xor(mv, 2));
            mv = fmaxf(mv, __shfl_xor(mv, 4));
            mv = fmaxf(mv, __shfl_xor(mv, 8));
            float mn = fmaxf(m_r[r], mv);
            alpha[r] = exp2f((m_r[r] - mn) * LOG2E);
            m_r[r] = mn;
            float rs = 0.f;
#pragma unroll
            for (int nt = 0; nt < 4; ++nt) {
                float p = exp2f((s[nt][r] - mn) * LOG2E);
                s[nt][r] = p;
                rs += p;
            }
            rs += __shfl_xor(rs, 1);
            rs += __shfl_xor(rs, 2);
            rs += __shfl_xor(rs, 4);
            rs += __shfl_xor(rs, 8);
            l_r[r] = l_r[r] * alpha[r] + rs;
        }

#pragma unroll
        for (int nt = 0; nt < 4; ++nt)
#pragma unroll
            for (int r = 0; r < 4; ++r)
                Pl[(wave * 16 + quad * 4 + r) * LDK + nt * 16 + tl] = f2b(s[nt][r]);

#pragma unroll
        for (int d = 0; d < 4; ++d)
#pragma unroll
            for (int r = 0; r < 4; ++r) oacc[d][r] *= alpha[r];

        __syncthreads();   // fence u16 P-stores vs v8s P-loads

        v8s pf0 = *(const v8s*)&Pl[(wave * 16 + tl) * LDK + quad * 8];
        v8s pf1 = *(const v8s*)&Pl[(wave * 16 + tl) * LDK + 32 + quad * 8];
#pragma unroll
        for (int d = 0; d < 4; ++d) {
            v8s v0 = *(const v8s*)&Vtl[(d * 16 + tl) * LDK + quad * 8];
            v8s v1 = *(const v8s*)&Vtl[(d * 16 + tl) * LDK + 32 + quad * 8];
            oacc[d] = __builtin_amdgcn_mfma_f32_16x16x32_bf16(pf0, v0, oacc[d], 0, 0, 0);
            oacc[d] = __builtin_amdgcn_mfma_f32_16x16x32_bf16(pf1, v1, oacc[d], 0, 0, 0);
        }
        __syncthreads();   // protect Kl/Vtl before restage
    }

#pragma unroll
    for (int d = 0; d < 4; ++d)
#pragma unroll
        for (int r = 0; r < 4; ++r) {
            float vv = oacc[d][r] / l_r[r];
            ob[(size_t)(qr0 + quad * 4 + r) * os + d * 16 + tl] = f2b(vv);
        }
}

// ---------------------------------------------------------------------------
// out = LayerNorm(x + h) * g + b   over D=1024. grid 4096, 256 thr.
// XF32: x fp32 else bf16.  OF32: out fp32 else bf16.  h always bf16.
// ---------------------------------------------------------------------------
template <int XF32, int OF32>
__global__ __launch_bounds__(256) void add_ln(
    const void* __restrict__ Xv, const u16* __restrict__ Hh,
    const float* __restrict__ G, const float* __restrict__ Bb,
    void* __restrict__ Outv)
{
    const int row = blockIdx.x, t = threadIdx.x;
    float v0, v1, v2, v3;
    {
        ushort4 hv = *(const ushort4*)&Hh[(size_t)row * 1024 + t * 4];
        if (XF32) {
            const float* xr = (const float*)Xv + (size_t)row * 1024;
            float4 xv = *(const float4*)&xr[t * 4];
            v0 = xv.x + b2f(hv.x); v1 = xv.y + b2f(hv.y);
            v2 = xv.z + b2f(hv.z); v3 = xv.w + b2f(hv.w);
        } else {
            const u16* xr = (const u16*)Xv + (size_t)row * 1024;
            ushort4 xv = *(const ushort4*)&xr[t * 4];
            v0 = b2f(xv.x) + b2f(hv.x); v1 = b2f(xv.y) + b2f(hv.y);
            v2 = b2f(xv.z) + b2f(hv.z); v3 = b2f(xv.w) + b2f(hv.w);
        }
    }

    float s1 = v0 + v1 + v2 + v3;
    float s2 = v0 * v0 + v1 * v1 + v2 * v2 + v3 * v3;
#pragma unroll
    for (int o = 1; o < 64; o <<= 1) {
        s1 += __shfl_xor(s1, o);
        s2 += __shfl_xor(s2, o);
    }
    __shared__ float red[8];
    const int wave = t >> 6, lane = t & 63;
    if (lane == 0) { red[wave] = s1; red[4 + wave] = s2; }
    __syncthreads();
    s1 = red[0] + red[1] + red[2] + red[3];
    s2 = red[4] + red[5] + red[6] + red[7];

    const float mu = s1 * (1.f / 1024.f);
    float var = s2 * (1.f / 1024.f) - mu * mu;
    var = fmaxf(var, 0.f);
    const float rs = rsqrtf(var + 1e-5f);

    float4 gv = *(const float4*)&G[t * 4];
    float4 bv = *(const float4*)&Bb[t * 4];
    float o0 = (v0 - mu) * rs * gv.x + bv.x;
    float o1 = (v1 - mu) * rs * gv.y + bv.y;
    float o2 = (v2 - mu) * rs * gv.z + bv.z;
    float o3 = (v3 - mu) * rs * gv.w + bv.w;

    if (OF32) {
        float4 ov = {o0, o1, o2, o3};
        *(float4*)&((float*)Outv)[(size_t)row * 1024 + t * 4] = ov;
    } else {
        ushort4 ov;
        ov.x = f2b(o0); ov.y = f2b(o1); ov.z = f2b(o2); ov.w = f2b(o3);
        *(ushort4*)&((u16*)Outv)[(size_t)row * 1024 + t * 4] = ov;
    }
}

// ---------------------------------------------------------------------------
extern "C" void kernel_launch(void* const* d_in, const int* in_sizes, int n_in,
                              void* d_out, int out_size, void* d_ws, size_t ws_size,
                              hipStream_t stream) {
    const float* x0  = (const float*)d_in[0];   // [4096,1024] fp32
    const float* enc = (const float*)d_in[1];   // [4096,1024] fp32

    char* wsb = (char*)d_ws;
    const size_t MB = 1024u * 1024u;
    // persistent bf16 weights (byte offsets)
    u16*   wt_sa   = (u16*)(wsb);             // [3072][1024]  6 MB
    u16*   wt_caq  = (u16*)(wsb + 6  * MB);   // [1024][1024]  2 MB
    u16*   wt_cakv = (u16*)(wsb + 8  * MB);   // [2048][1024]  4 MB
    float* sab     = (float*)(wsb + 12 * MB);           // [3072]
    float* cakvb   = (float*)(wsb + 12 * MB + 16384);   // [2048]
    char*  arena   = wsb + 12 * MB + 32768;
    // arena (bf16 activations, overlapping lifetimes)
    u16* QKV    = (u16*)(arena);            // [4096][3072] 24 MB (dead after attn1)
    u16* hbuf   = (u16*)(arena + 24 * MB);  // [4096][1024]  8 MB
    u16* x1     = (u16*)(arena + 32 * MB);  // [4096][1024]  8 MB (dead after ln2)
    u16* Q2     = (u16*)(arena);            // [4096][1024]  (reuses QKV)
    u16* KV2    = (u16*)(arena + 8  * MB);  // [4096][2048]  (reuses QKV)
    u16* x2     = (u16*)(arena);            // [4096][1024]  (reuses Q2)
    u16* wt_fc1 = (u16*)(arena + 8  * MB);  // [4096][1024]  (dead KV2)
    u16* wt_fc2 = (u16*)(arena + 16 * MB);  // [1024][4096]  (dead KV2)
    u16* tbuf   = (u16*)(arena + 24 * MB);  // [2048][4096]  (dead hbuf+x1)
    u16* h3     = (u16*)(arena + 40 * MB);  // [4096][1024]
    // total ~60 MB

    prep_bias<<<4, 256, 0, stream>>>(
        (const float*)d_in[3], (const float*)d_in[5], (const float*)d_in[7],
        (const float*)d_in[13], (const float*)d_in[15], sab, cakvb);

    transpose_f2b<<<dim3(32, 32), 256, 0, stream>>>((const float*)d_in[2],  wt_sa,               1024, 1024);
    transpose_f2b<<<dim3(32, 32), 256, 0, stream>>>((const float*)d_in[4],  wt_sa + 1024*1024,   1024, 1024);
    transpose_f2b<<<dim3(32, 32), 256, 0, stream>>>((const float*)d_in[6],  wt_sa + 2*1024*1024, 1024, 1024);
    transpose_f2b<<<dim3(32, 32), 256, 0, stream>>>((const float*)d_in[10], wt_caq,              1024, 1024);
    transpose_f2b<<<dim3(32, 32), 256, 0, stream>>>((const float*)d_in[12], wt_cakv,             1024, 1024);
    transpose_f2b<<<dim3(32, 32), 256, 0, stream>>>((const float*)d_in[14], wt_cakv + 1024*1024, 1024, 1024);

    // --- self-attention block ---
    gemm_bt<1><<<dim3(24, 32), 256, 0, stream>>>(x0, wt_sa, sab, QKV, 4096, 3072, 1024, 0);
    attn64<<<dim3(32, 32), 256, 0, stream>>>(QKV, 3072, QKV + 1024, 3072, QKV + 2048, 3072,
                                             hbuf, 1024, 2048, 0.125f);
    add_ln<1, 0><<<4096, 256, 0, stream>>>(x0, hbuf, (const float*)d_in[8], (const float*)d_in[9], x1);

    // --- cross-attention block ---
    gemm_bt<0><<<dim3(8, 32), 256, 0, stream>>>(x1, wt_caq, (const float*)d_in[11], Q2, 4096, 1024, 1024, 0);
    gemm_bt<1><<<dim3(16, 32), 256, 0, stream>>>(enc, wt_cakv, cakvb, KV2, 4096, 2048, 1024, 0);
    attn64<<<dim3(32, 32), 256, 0, stream>>>(Q2, 1024, KV2, 2048, KV2 + 1024, 2048,
                                             hbuf, 1024, 2048, 0.125f);
    add_ln<0, 0><<<4096, 256, 0, stream>>>(x1, hbuf, (const float*)d_in[16], (const float*)d_in[17], x2);

    // --- FFN block (two M=2048 halves; tbuf reused) ---
    transpose_f2b<<<dim3(128, 32), 256, 0, stream>>>((const float*)d_in[18], wt_fc1, 1024, 4096);
    transpose_f2b<<<dim3(32, 128), 256, 0, stream>>>((const float*)d_in[20], wt_fc2, 4096, 1024);
    for (int hf = 0; hf < 2; ++hf) {
        const u16* xh = x2 + (size_t)hf * 2048 * 1024;
        u16*       oh = h3 + (size_t)hf * 2048 * 1024;
        gemm_bt<0><<<dim3(32, 16), 256, 0, stream>>>(xh, wt_fc1, (const float*)d_in[19], tbuf, 2048, 4096, 1024, 1);
        gemm_bt<0><<<dim3(8, 16), 256, 0, stream>>>(tbuf, wt_fc2, (const float*)d_in[21], oh, 2048, 1024, 4096, 0);
    }
    add_ln<0, 1><<<4096, 256, 0, stream>>>(x2, h3, (const float*)d_in[22], (const float*)d_in[23], d_out);
}